// Round 4
// baseline (6899.291 us; speedup 1.0000x reference)
//
#include <hip/hip_runtime.h>

#define LAYERS 6
#define NN 9
#define NHEAD 8
#define HD 16

// ---------------------------------------------------------------------------
// K0: precompute per-layer/head  M_h = 0.25 * Aq_h @ Ak_h^T  (9x9)
//                                N_h = Av_h @ Wo_h           (9x9)
// MN layout: [l][h][2][81]
// ---------------------------------------------------------------------------
__global__ void k_precompute(const float* __restrict__ Wq, const float* __restrict__ Wk,
                             const float* __restrict__ Wv, const float* __restrict__ Wo,
                             float* __restrict__ MN)
{
    const int l  = blockIdx.x;   // 0..5
    const int ht = blockIdx.y;   // 0..7
    const int t  = threadIdx.x;  // 0..191
    if (t < 81) {
        const int a = t / 9, b = t % 9;
        float s = 0.f;
        for (int d = 0; d < HD; ++d)
            s += Wq[(l * NN + a) * 128 + ht * HD + d] * Wk[(l * NN + b) * 128 + ht * HD + d];
        MN[((size_t)(l * NHEAD + ht) * 2 + 0) * 81 + t] = s * 0.25f;
    } else if (t < 162) {
        const int u = t - 81;
        const int a = u / 9, b = u % 9;
        float s = 0.f;
        for (int d = 0; d < HD; ++d)
            s += Wv[(l * NN + a) * 128 + ht * HD + d] * Wo[((size_t)l * 128 + ht * HD + d) * NN + b];
        MN[((size_t)(l * NHEAD + ht) * 2 + 1) * 81 + u] = s;
    }
}

// ---------------------------------------------------------------------------
// K1: transformer, one thread per batch element.
// Register-pressure-restructured vs the 3701us baseline: per-row attention
// (T[9] not T[81]) and per-row fused FFN+LN2 (9-float accumulator) keep live
// state ~190 floats -> no scratch spills (baseline: 243 live floats, 3 GB of
// spill traffic per dispatch = its entire runtime).
// ALL layers' weights staged to LDS once at entry (67 KB/block; grid is
// 1 block/CU so occupancy is grid-limited anyway) -> exactly ONE
// __syncthreads() in the kernel, no barrier inside any loop.
// BUGFIX vs prev round: sB/sBf1 staging is now grid-stride (previous if/else
// chain needed 294 threads for 256 available -> sBf1[5][2..39] was
// uninitialized LDS -> absmax 6.6).
// ---------------------------------------------------------------------------
__global__ void __launch_bounds__(256, 1) k_transformer(
    const float* __restrict__ xg, const float* __restrict__ MN,
    const float* __restrict__ bo,
    const float* __restrict__ ln1g, const float* __restrict__ ln1b,
    const float* __restrict__ ln2g, const float* __restrict__ ln2b,
    const float* __restrict__ Wf1, const float* __restrict__ bf1,
    const float* __restrict__ Wf2, const float* __restrict__ bf2,
    float* __restrict__ scratch, int Bn, int layout_soa)
{
    // sM[l][ht][k][m] = M_ht[m][k] (transposed), rows padded to 12 floats
    // sN[l][ht][c][j] = N_ht[c][j]
    // sWf1[l][f][m]   = Wf1[m][f]  (transposed)
    // sWf2[l][f][j]   = Wf2[f][j]
    // sB[l][0..5][j]  = bo, ln1g, ln1b, ln2g, ln2b, bf2
    __shared__ __align__(16) float sM[LAYERS][NHEAD][9][12];
    __shared__ __align__(16) float sN[LAYERS][NHEAD][9][12];
    __shared__ __align__(16) float sWf1[LAYERS][40][12];
    __shared__ __align__(16) float sWf2[LAYERS][40][12];
    __shared__ float sB[LAYERS][6][9];
    __shared__ float sBf1[LAYERS][40];

    const int tid = threadIdx.x;
    const int b = blockIdx.x * 256 + tid;
    const bool active = (b < Bn);
    const float* __restrict__ xp = xg + (size_t)b * NN;

    // ---- stage ALL weights into LDS (once); every loop is grid-stride ----
    for (int t = tid; t < LAYERS * NHEAD * 81; t += 256) {          // 3888
        const int l = t / (NHEAD * 81);
        const int rem = t % (NHEAD * 81);
        const int ht = rem / 81, idx = rem % 81;
        const int r = idx / 9, c = idx % 9;
        sM[l][ht][c][r] = MN[((size_t)(l * NHEAD + ht) * 2 + 0) * 81 + idx]; // transpose
        sN[l][ht][r][c] = MN[((size_t)(l * NHEAD + ht) * 2 + 1) * 81 + idx];
    }
    for (int t = tid; t < LAYERS * 360; t += 256) {                  // 2160
        const int l = t / 360;
        const int rem = t % 360;
        const int m = rem / 40, f = rem % 40;
        sWf1[l][f][m] = Wf1[((size_t)l * 9 + m) * 40 + f];           // transpose
        const int f2 = rem / 9, j = rem % 9;
        sWf2[l][f2][j] = Wf2[((size_t)l * 40 + f2) * 9 + j];
    }
    for (int t = tid; t < LAYERS * 9; t += 256) {                    // 54
        const int l = t / 9, j = t % 9;
        sB[l][0][j] = bo[l * 9 + j];
        sB[l][1][j] = ln1g[l * 9 + j];
        sB[l][2][j] = ln1b[l * 9 + j];
        sB[l][3][j] = ln2g[l * 9 + j];
        sB[l][4][j] = ln2b[l * 9 + j];
        sB[l][5][j] = bf2[l * 9 + j];
    }
    for (int u = tid; u < LAYERS * 40; u += 256) {                   // 240
        sBf1[u / 40][u % 40] = bf1[u];
    }
    __syncthreads();   // the only barrier in this kernel

    if (!active) return;

    float h[81];
#pragma unroll
    for (int i = 0; i < 9; ++i) {
        const float xv = xp[i];
#pragma unroll
        for (int j = 0; j < 9; ++j) h[i * 9 + j] = (i == j) ? xv : 0.f;
    }

#pragma unroll 1
    for (int l = 0; l < LAYERS; ++l) {
        // ---- attention: acc = sum_ht softmax(h M_ht h^T) h N_ht ----
        float acc[81];
#pragma unroll
        for (int i = 0; i < 81; ++i) acc[i] = 0.f;

#pragma unroll 1
        for (int ht = 0; ht < NHEAD; ++ht) {
#pragma unroll
            for (int a = 0; a < 9; ++a) {
                float T[9];
#pragma unroll
                for (int k = 0; k < 9; ++k) {
                    float s = 0.f;
#pragma unroll
                    for (int m = 0; m < 9; ++m) s += h[a * 9 + m] * sM[l][ht][k][m];
                    T[k] = s;
                }
                float sr[9];
#pragma unroll
                for (int j = 0; j < 9; ++j) {
                    float s = 0.f;
#pragma unroll
                    for (int k = 0; k < 9; ++k) s += T[k] * h[j * 9 + k];
                    sr[j] = s;
                }
                float mx = sr[0];
#pragma unroll
                for (int j = 1; j < 9; ++j) mx = fmaxf(mx, sr[j]);
                float sum = 0.f;
#pragma unroll
                for (int j = 0; j < 9; ++j) { sr[j] = __expf(sr[j] - mx); sum += sr[j]; }
                const float inv = __builtin_amdgcn_rcpf(sum);
#pragma unroll
                for (int j = 0; j < 9; ++j) sr[j] *= inv;
                float qr[9];
#pragma unroll
                for (int c = 0; c < 9; ++c) {
                    float s = 0.f;
#pragma unroll
                    for (int k = 0; k < 9; ++k) s += sr[k] * h[k * 9 + c];
                    qr[c] = s;
                }
#pragma unroll
                for (int c = 0; c < 9; ++c) {
                    const float qv = qr[c];
#pragma unroll
                    for (int j = 0; j < 9; ++j) acc[a * 9 + j] += qv * sN[l][ht][c][j];
                }
            }
        }

        // ---- h = LN1(h + acc + bo) ----
#pragma unroll
        for (int a = 0; a < 9; ++a) {
            float r[9]; float mean = 0.f;
#pragma unroll
            for (int j = 0; j < 9; ++j) { r[j] = h[a * 9 + j] + acc[a * 9 + j] + sB[l][0][j]; mean += r[j]; }
            mean *= (1.f / 9.f);
            float var = 0.f;
#pragma unroll
            for (int j = 0; j < 9; ++j) { const float d = r[j] - mean; var += d * d; }
            var *= (1.f / 9.f);
            const float rs = __builtin_amdgcn_rsqf(var + 1e-5f);
#pragma unroll
            for (int j = 0; j < 9; ++j) h[a * 9 + j] = (r[j] - mean) * rs * sB[l][1][j] + sB[l][2][j];
        }

        // ---- FFN + LN2, row at a time (9-float accumulator) ----
#pragma unroll
        for (int a = 0; a < 9; ++a) {
            float accr[9];
#pragma unroll
            for (int j = 0; j < 9; ++j) accr[j] = 0.f;
#pragma unroll 4
            for (int f = 0; f < 40; ++f) {
                float s = sBf1[l][f];
#pragma unroll
                for (int m = 0; m < 9; ++m) s += h[a * 9 + m] * sWf1[l][f][m];
                s = fmaxf(s, 0.f);
#pragma unroll
                for (int j = 0; j < 9; ++j) accr[j] += s * sWf2[l][f][j];
            }
            float r[9]; float mean = 0.f;
#pragma unroll
            for (int j = 0; j < 9; ++j) { r[j] = h[a * 9 + j] + accr[j] + sB[l][5][j]; mean += r[j]; }
            mean *= (1.f / 9.f);
            float var = 0.f;
#pragma unroll
            for (int j = 0; j < 9; ++j) { const float d = r[j] - mean; var += d * d; }
            var *= (1.f / 9.f);
            const float rs = __builtin_amdgcn_rsqf(var + 1e-5f);
#pragma unroll
            for (int j = 0; j < 9; ++j) h[a * 9 + j] = (r[j] - mean) * rs * sB[l][3][j] + sB[l][4][j];
        }
    }

    // ---- write adj (=h) and z = adj @ x ----
    if (layout_soa) {
#pragma unroll
        for (int i = 0; i < 81; ++i) scratch[(size_t)i * Bn + b] = h[i];
#pragma unroll
        for (int a = 0; a < 9; ++a) {
            float s = 0.f;
#pragma unroll
            for (int k = 0; k < 9; ++k) s += h[a * 9 + k] * xp[k];
            scratch[(size_t)(81 + a) * Bn + b] = s;
        }
    } else {
        float* op = scratch + (size_t)b * 1440;
#pragma unroll
        for (int i = 0; i < 81; ++i) op[i] = h[i];
#pragma unroll
        for (int a = 0; a < 9; ++a) {
            float s = 0.f;
#pragma unroll
            for (int k = 0; k < 9; ++k) s += h[a * 9 + k] * xp[k];
            op[81 + a] = s;
        }
    }
}

// ---------------------------------------------------------------------------
// K2: GCN, one 64-lane wave per batch element. (unchanged)
// ---------------------------------------------------------------------------
__global__ void __launch_bounds__(64) k_gcn(
    const float* __restrict__ scratch, const float* __restrict__ w1,
    const float* __restrict__ Wg1, const float* __restrict__ Wg2,
    float* __restrict__ out, int Bn, int layout_soa)
{
    __shared__ float adjs[81];
    __shared__ float zs[9];
    __shared__ float m2s[9 * 40];
    __shared__ float y1s[9 * 80];
    __shared__ float m3s[9 * 80];

    const int b = blockIdx.x;
    const int l = threadIdx.x;

    if (layout_soa) {
        adjs[l] = scratch[(size_t)l * Bn + b];
        if (l < 17) adjs[64 + l] = scratch[(size_t)(64 + l) * Bn + b];
        if (l < 9)  zs[l] = scratch[(size_t)(81 + l) * Bn + b];
    } else {
        const float* src = scratch + (size_t)b * 1440;
        adjs[l] = src[l];
        if (l < 17) adjs[64 + l] = src[64 + l];
        if (l < 9)  zs[l] = src[81 + l];
    }
    __syncthreads();

    // stage 1: m2[a][c] = sum_k adj[a][k] * LR(z[k]*w1[c])
    for (int o = l; o < 360; o += 64) {
        const int c = o / 9, a = o - c * 9;
        const float wc = w1[c];
        float s = 0.f;
#pragma unroll
        for (int k = 0; k < 9; ++k) {
            float nv = zs[k] * wc;
            nv = nv > 0.f ? nv : 0.2f * nv;
            s += adjs[a * 9 + k] * nv;
        }
        m2s[a * 40 + c] = s;
    }
    __syncthreads();

    // stage 2: y1[a][j] = LR( sum_f m2[a][f] * Wg1[f][j] )
    for (int j = l; j < 80; j += 64) {
        float acc[9];
#pragma unroll
        for (int a = 0; a < 9; ++a) acc[a] = 0.f;
        for (int f = 0; f < 40; f += 4) {
            const float w0 = Wg1[(size_t)f * 80 + j];
            const float wA = Wg1[(size_t)(f + 1) * 80 + j];
            const float wB = Wg1[(size_t)(f + 2) * 80 + j];
            const float wC = Wg1[(size_t)(f + 3) * 80 + j];
#pragma unroll
            for (int a = 0; a < 9; ++a) {
                const float4 v = *reinterpret_cast<const float4*>(&m2s[a * 40 + f]);
                acc[a] += v.x * w0 + v.y * wA + v.z * wB + v.w * wC;
            }
        }
#pragma unroll
        for (int a = 0; a < 9; ++a) {
            const float t = acc[a];
            y1s[a * 80 + j] = t > 0.f ? t : 0.2f * t;
        }
    }
    __syncthreads();

    // hoist adj into registers for stage 3
    float ar[81];
#pragma unroll
    for (int i = 0; i < 81; ++i) ar[i] = adjs[i];

    // stage 3: m3[a][j] = sum_k adj[a][k] * y1[k][j]
    for (int j = l; j < 80; j += 64) {
        float acc[9];
#pragma unroll
        for (int a = 0; a < 9; ++a) acc[a] = 0.f;
#pragma unroll
        for (int k = 0; k < 9; ++k) {
            const float yv = y1s[k * 80 + j];
#pragma unroll
            for (int a = 0; a < 9; ++a) acc[a] += ar[a * 9 + k] * yv;
        }
#pragma unroll
        for (int a = 0; a < 9; ++a) m3s[a * 80 + j] = acc[a];
    }
    __syncthreads();

    // stage 4: y2[a][c] = LR( sum_f m3[a][f] * Wg2[f][c] ) -> out
    float a0[9], a1[9], a2[9];
#pragma unroll
    for (int a = 0; a < 9; ++a) { a0[a] = 0.f; a1[a] = 0.f; a2[a] = 0.f; }
    const bool h2 = (l < 32);
    const int c0 = l, c1 = l + 64, c2 = l + 128;
    for (int f = 0; f < 80; f += 4) {
        float wA[4], wB[4], wC[4];
#pragma unroll
        for (int q = 0; q < 4; ++q) {
            wA[q] = Wg2[(size_t)(f + q) * 160 + c0];
            wB[q] = Wg2[(size_t)(f + q) * 160 + c1];
            wC[q] = h2 ? Wg2[(size_t)(f + q) * 160 + c2] : 0.f;
        }
#pragma unroll
        for (int a = 0; a < 9; ++a) {
            const float4 v = *reinterpret_cast<const float4*>(&m3s[a * 80 + f]);
            a0[a] += v.x * wA[0] + v.y * wA[1] + v.z * wA[2] + v.w * wA[3];
            a1[a] += v.x * wB[0] + v.y * wB[1] + v.z * wB[2] + v.w * wB[3];
            a2[a] += v.x * wC[0] + v.y * wC[1] + v.z * wC[2] + v.w * wC[3];
        }
    }
    float* op = out + (size_t)b * 1440;
#pragma unroll
    for (int a = 0; a < 9; ++a) {
        const float t0 = a0[a]; op[a * 160 + c0] = t0 > 0.f ? t0 : 0.2f * t0;
        const float t1 = a1[a]; op[a * 160 + c1] = t1 > 0.f ? t1 : 0.2f * t1;
        if (h2) { const float t2 = a2[a]; op[a * 160 + c2] = t2 > 0.f ? t2 : 0.2f * t2; }
    }
}

// ---------------------------------------------------------------------------
extern "C" void kernel_launch(void* const* d_in, const int* in_sizes, int n_in,
                              void* d_out, int out_size, void* d_ws, size_t ws_size,
                              hipStream_t stream)
{
    const float* x    = (const float*)d_in[0];
    const float* Wq   = (const float*)d_in[2];
    const float* Wk   = (const float*)d_in[4];
    const float* Wv   = (const float*)d_in[6];
    const float* Wo   = (const float*)d_in[8];
    const float* bo   = (const float*)d_in[9];
    const float* ln1g = (const float*)d_in[10];
    const float* ln1b = (const float*)d_in[11];
    const float* ln2g = (const float*)d_in[12];
    const float* ln2b = (const float*)d_in[13];
    const float* Wf1  = (const float*)d_in[14];
    const float* bf1  = (const float*)d_in[15];
    const float* Wf2  = (const float*)d_in[16];
    const float* bf2  = (const float*)d_in[17];
    const float* wg1c = (const float*)d_in[18];  // W_gcn1 [1,40]
    const float* Wg1  = (const float*)d_in[19];  // [40,80]
    const float* Wg2  = (const float*)d_in[20];  // [80,160]

    const int Bn = in_sizes[0] / NN;

    float* MN = (float*)d_ws;                    // 7776 floats
    const size_t mn_floats = (size_t)LAYERS * NHEAD * 2 * 81;
    const size_t need = (mn_floats + (size_t)Bn * 90) * sizeof(float);
    const int use_ws_scratch = (ws_size >= need) ? 1 : 0;
    float* adjz = use_ws_scratch ? (MN + mn_floats) : (float*)d_out;

    k_precompute<<<dim3(LAYERS, NHEAD), 192, 0, stream>>>(Wq, Wk, Wv, Wo, MN);

    const int nblk = (Bn + 255) / 256;
    k_transformer<<<nblk, 256, 0, stream>>>(x, MN, bo, ln1g, ln1b, ln2g, ln2b,
                                            Wf1, bf1, Wf2, bf2, adjz, Bn, use_ws_scratch);

    k_gcn<<<Bn, 64, 0, stream>>>(adjz, wg1c, Wg1, Wg2, (float*)d_out, Bn, use_ws_scratch);
}

// Round 5
// 2044.511 us; speedup vs baseline: 3.3745x; 3.3745x over previous
//
#include <hip/hip_runtime.h>

#define LAYERS 6
#define NN 9
#define NHEAD 8
#define HD 16

// ---------------------------------------------------------------------------
// K0: precompute per-layer/head  M_h = 0.25 * Aq_h @ Ak_h^T  (9x9)
//                                N_h = Av_h @ Wo_h           (9x9)
// MN layout: [l][h][2][81]
// ---------------------------------------------------------------------------
__global__ void k_precompute(const float* __restrict__ Wq, const float* __restrict__ Wk,
                             const float* __restrict__ Wv, const float* __restrict__ Wo,
                             float* __restrict__ MN)
{
    const int l  = blockIdx.x;   // 0..5
    const int ht = blockIdx.y;   // 0..7
    const int t  = threadIdx.x;  // 0..191
    if (t < 81) {
        const int a = t / 9, b = t % 9;
        float s = 0.f;
        for (int d = 0; d < HD; ++d)
            s += Wq[(l * NN + a) * 128 + ht * HD + d] * Wk[(l * NN + b) * 128 + ht * HD + d];
        MN[((size_t)(l * NHEAD + ht) * 2 + 0) * 81 + t] = s * 0.25f;
    } else if (t < 162) {
        const int u = t - 81;
        const int a = u / 9, b = u % 9;
        float s = 0.f;
        for (int d = 0; d < HD; ++d)
            s += Wv[(l * NN + a) * 128 + ht * HD + d] * Wo[((size_t)l * 128 + ht * HD + d) * NN + b];
        MN[((size_t)(l * NHEAD + ht) * 2 + 1) * 81 + u] = s;
    }
}

// ---------------------------------------------------------------------------
// K1: transformer, ROW-PER-LANE. 9 lanes own one batch element (one h-row
// each); 7 batch elements per wave (63/64 lanes), 4 waves/block = 28/block.
// Per-lane live state ~45 floats -> no spills possible (the one-thread-per-
// batch versions churned 3-7 GB of scratch; that structure is abandoned).
// h lives in a per-group LDS tile [9][12]; reads are group-broadcast float4
// (group bases hit disjoint banks -> conflict-free); one rewrite per layer.
// Wave-lockstep => ZERO barriers. Weights: wave-uniform global reads
// (scalar-loadable, L2-resident). Softmax/LN are row-local => lane-local.
// FMA order matches the verified baseline exactly.
// ---------------------------------------------------------------------------
__global__ void __launch_bounds__(256, 2) k_transformer(
    const float* __restrict__ xg, const float* __restrict__ MN,
    const float* __restrict__ bo,
    const float* __restrict__ ln1g, const float* __restrict__ ln1b,
    const float* __restrict__ ln2g, const float* __restrict__ ln2b,
    const float* __restrict__ Wf1, const float* __restrict__ bf1,
    const float* __restrict__ Wf2, const float* __restrict__ bf2,
    float* __restrict__ scratch, int Bn, int layout_soa)
{
    __shared__ __align__(16) float hT[4][7][9][12];   // [wave][group][row][col pad 12]

    const int tid  = threadIdx.x;
    const int wv   = tid >> 6;
    const int lane = tid & 63;
    const int g    = lane / 9;        // 0..6 active, 7 = idle lane 63
    const int a    = lane - g * 9;    // my row 0..8
    const int b    = (blockIdx.x * 4 + wv) * 7 + g;
    if (g >= 7 || b >= Bn) return;    // no barriers in kernel -> early return safe

    const float* __restrict__ xp = xg + (size_t)b * NN;
    float* myrow = &hT[wv][g][a][0];

    // ---- init: h = diag(x) ; publish my row ----
    float h[9];
    const float xa = xp[a];
#pragma unroll
    for (int j = 0; j < 9; ++j) h[j] = (j == a) ? xa : 0.f;
    *(float4*)(myrow)     = make_float4(h[0], h[1], h[2], h[3]);
    *(float4*)(myrow + 4) = make_float4(h[4], h[5], h[6], h[7]);
    myrow[8] = h[8];
    __builtin_amdgcn_wave_barrier();

#pragma unroll 1
    for (int l = 0; l < LAYERS; ++l) {
        float acc[9];
#pragma unroll
        for (int j = 0; j < 9; ++j) acc[j] = 0.f;

        // ---- attention: acc += softmax(h M h^T) h N, per head ----
#pragma unroll 1
        for (int ht = 0; ht < NHEAD; ++ht) {
            const float* __restrict__ Mw = MN + ((size_t)(l * NHEAD + ht) * 2) * 81;
            const float* __restrict__ Nw = Mw + 81;

            // T[k] = sum_m h[a][m] * M[m][k]   (h row is lane-local)
            float T[9];
#pragma unroll
            for (int k = 0; k < 9; ++k) T[k] = 0.f;
#pragma unroll
            for (int m = 0; m < 9; ++m) {
                const float hm = h[m];
#pragma unroll
                for (int k = 0; k < 9; ++k) T[k] += hm * Mw[m * 9 + k];
            }

            // S[j] = sum_k T[k] * h[j][k]  (other rows via LDS broadcast)
            float P[9];
#pragma unroll
            for (int j = 0; j < 9; ++j) {
                const float4 v0 = *(const float4*)&hT[wv][g][j][0];
                const float4 v1 = *(const float4*)&hT[wv][g][j][4];
                const float  v8 = hT[wv][g][j][8];
                float s = T[0] * v0.x;
                s += T[1] * v0.y; s += T[2] * v0.z; s += T[3] * v0.w;
                s += T[4] * v1.x; s += T[5] * v1.y; s += T[6] * v1.z; s += T[7] * v1.w;
                s += T[8] * v8;
                P[j] = s;
            }

            // softmax (row-local)
            float mx = P[0];
#pragma unroll
            for (int j = 1; j < 9; ++j) mx = fmaxf(mx, P[j]);
            float sum = 0.f;
#pragma unroll
            for (int j = 0; j < 9; ++j) { P[j] = __expf(P[j] - mx); sum += P[j]; }
            const float inv = __builtin_amdgcn_rcpf(sum);
#pragma unroll
            for (int j = 0; j < 9; ++j) P[j] *= inv;

            // Q[c] = sum_k P[k] * h[k][c]
            float Q[9];
#pragma unroll
            for (int c = 0; c < 9; ++c) Q[c] = 0.f;
#pragma unroll
            for (int k = 0; k < 9; ++k) {
                const float4 v0 = *(const float4*)&hT[wv][g][k][0];
                const float4 v1 = *(const float4*)&hT[wv][g][k][4];
                const float  v8 = hT[wv][g][k][8];
                const float pk = P[k];
                Q[0] += pk * v0.x; Q[1] += pk * v0.y; Q[2] += pk * v0.z; Q[3] += pk * v0.w;
                Q[4] += pk * v1.x; Q[5] += pk * v1.y; Q[6] += pk * v1.z; Q[7] += pk * v1.w;
                Q[8] += pk * v8;
            }

            // acc[j] += sum_c Q[c] * N[c][j]
#pragma unroll
            for (int c = 0; c < 9; ++c) {
                const float qc = Q[c];
#pragma unroll
                for (int j = 0; j < 9; ++j) acc[j] += qc * Nw[c * 9 + j];
            }
        }

        // ---- LN1 (row-local) ----
        {
            const float* bop = bo   + l * 9;
            const float* g1  = ln1g + l * 9;
            const float* b1  = ln1b + l * 9;
            float r[9]; float mean = 0.f;
#pragma unroll
            for (int j = 0; j < 9; ++j) { r[j] = h[j] + acc[j] + bop[j]; mean += r[j]; }
            mean *= (1.f / 9.f);
            float var = 0.f;
#pragma unroll
            for (int j = 0; j < 9; ++j) { const float d = r[j] - mean; var += d * d; }
            var *= (1.f / 9.f);
            const float rs = __builtin_amdgcn_rsqf(var + 1e-5f);
#pragma unroll
            for (int j = 0; j < 9; ++j) h[j] = (r[j] - mean) * rs * g1[j] + b1[j];
        }

        // ---- FFN + LN2 (row-local; h row in registers) ----
        {
            const float* wf1 = Wf1 + (size_t)l * 9 * 40;
            const float* wf2 = Wf2 + (size_t)l * 40 * 9;
            const float* bp1 = bf1 + l * 40;
            float accr[9];
#pragma unroll
            for (int j = 0; j < 9; ++j) accr[j] = 0.f;
#pragma unroll 4
            for (int f = 0; f < 40; ++f) {
                float s = bp1[f];
#pragma unroll
                for (int m = 0; m < 9; ++m) s += h[m] * wf1[m * 40 + f];
                s = fmaxf(s, 0.f);
#pragma unroll
                for (int j = 0; j < 9; ++j) accr[j] += s * wf2[f * 9 + j];
            }
            const float* bp2 = bf2  + l * 9;
            const float* g2  = ln2g + l * 9;
            const float* b2  = ln2b + l * 9;
            float r[9]; float mean = 0.f;
#pragma unroll
            for (int j = 0; j < 9; ++j) { r[j] = h[j] + accr[j] + bp2[j]; mean += r[j]; }
            mean *= (1.f / 9.f);
            float var = 0.f;
#pragma unroll
            for (int j = 0; j < 9; ++j) { const float d = r[j] - mean; var += d * d; }
            var *= (1.f / 9.f);
            const float rs = __builtin_amdgcn_rsqf(var + 1e-5f);
#pragma unroll
            for (int j = 0; j < 9; ++j) h[j] = (r[j] - mean) * rs * g2[j] + b2[j];
        }

        // ---- publish updated row for next layer's attention ----
        if (l < LAYERS - 1) {
            __builtin_amdgcn_wave_barrier();
            *(float4*)(myrow)     = make_float4(h[0], h[1], h[2], h[3]);
            *(float4*)(myrow + 4) = make_float4(h[4], h[5], h[6], h[7]);
            myrow[8] = h[8];
            __builtin_amdgcn_wave_barrier();
        }
    }

    // ---- write adj row (=h) and z[a] = adj_row . x ----
    if (layout_soa) {
#pragma unroll
        for (int j = 0; j < 9; ++j) scratch[(size_t)(a * 9 + j) * Bn + b] = h[j];
        float z = 0.f;
#pragma unroll
        for (int k = 0; k < 9; ++k) z += h[k] * xp[k];
        scratch[(size_t)(81 + a) * Bn + b] = z;
    } else {
        float* op = scratch + (size_t)b * 1440;
#pragma unroll
        for (int j = 0; j < 9; ++j) op[a * 9 + j] = h[j];
        float z = 0.f;
#pragma unroll
        for (int k = 0; k < 9; ++k) z += h[k] * xp[k];
        op[81 + a] = z;
    }
}

// ---------------------------------------------------------------------------
// K2: GCN, one 64-lane wave per batch element. (unchanged)
// ---------------------------------------------------------------------------
__global__ void __launch_bounds__(64) k_gcn(
    const float* __restrict__ scratch, const float* __restrict__ w1,
    const float* __restrict__ Wg1, const float* __restrict__ Wg2,
    float* __restrict__ out, int Bn, int layout_soa)
{
    __shared__ float adjs[81];
    __shared__ float zs[9];
    __shared__ float m2s[9 * 40];
    __shared__ float y1s[9 * 80];
    __shared__ float m3s[9 * 80];

    const int b = blockIdx.x;
    const int l = threadIdx.x;

    if (layout_soa) {
        adjs[l] = scratch[(size_t)l * Bn + b];
        if (l < 17) adjs[64 + l] = scratch[(size_t)(64 + l) * Bn + b];
        if (l < 9)  zs[l] = scratch[(size_t)(81 + l) * Bn + b];
    } else {
        const float* src = scratch + (size_t)b * 1440;
        adjs[l] = src[l];
        if (l < 17) adjs[64 + l] = src[64 + l];
        if (l < 9)  zs[l] = src[81 + l];
    }
    __syncthreads();

    // stage 1: m2[a][c] = sum_k adj[a][k] * LR(z[k]*w1[c])
    for (int o = l; o < 360; o += 64) {
        const int c = o / 9, a = o - c * 9;
        const float wc = w1[c];
        float s = 0.f;
#pragma unroll
        for (int k = 0; k < 9; ++k) {
            float nv = zs[k] * wc;
            nv = nv > 0.f ? nv : 0.2f * nv;
            s += adjs[a * 9 + k] * nv;
        }
        m2s[a * 40 + c] = s;
    }
    __syncthreads();

    // stage 2: y1[a][j] = LR( sum_f m2[a][f] * Wg1[f][j] )
    for (int j = l; j < 80; j += 64) {
        float acc[9];
#pragma unroll
        for (int a = 0; a < 9; ++a) acc[a] = 0.f;
        for (int f = 0; f < 40; f += 4) {
            const float w0 = Wg1[(size_t)f * 80 + j];
            const float wA = Wg1[(size_t)(f + 1) * 80 + j];
            const float wB = Wg1[(size_t)(f + 2) * 80 + j];
            const float wC = Wg1[(size_t)(f + 3) * 80 + j];
#pragma unroll
            for (int a = 0; a < 9; ++a) {
                const float4 v = *reinterpret_cast<const float4*>(&m2s[a * 40 + f]);
                acc[a] += v.x * w0 + v.y * wA + v.z * wB + v.w * wC;
            }
        }
#pragma unroll
        for (int a = 0; a < 9; ++a) {
            const float t = acc[a];
            y1s[a * 80 + j] = t > 0.f ? t : 0.2f * t;
        }
    }
    __syncthreads();

    // hoist adj into registers for stage 3
    float ar[81];
#pragma unroll
    for (int i = 0; i < 81; ++i) ar[i] = adjs[i];

    // stage 3: m3[a][j] = sum_k adj[a][k] * y1[k][j]
    for (int j = l; j < 80; j += 64) {
        float acc[9];
#pragma unroll
        for (int a = 0; a < 9; ++a) acc[a] = 0.f;
#pragma unroll
        for (int k = 0; k < 9; ++k) {
            const float yv = y1s[k * 80 + j];
#pragma unroll
            for (int a = 0; a < 9; ++a) acc[a] += ar[a * 9 + k] * yv;
        }
#pragma unroll
        for (int a = 0; a < 9; ++a) m3s[a * 80 + j] = acc[a];
    }
    __syncthreads();

    // stage 4: y2[a][c] = LR( sum_f m3[a][f] * Wg2[f][c] ) -> out
    float a0[9], a1[9], a2[9];
#pragma unroll
    for (int a = 0; a < 9; ++a) { a0[a] = 0.f; a1[a] = 0.f; a2[a] = 0.f; }
    const bool h2 = (l < 32);
    const int c0 = l, c1 = l + 64, c2 = l + 128;
    for (int f = 0; f < 80; f += 4) {
        float wA[4], wB[4], wC[4];
#pragma unroll
        for (int q = 0; q < 4; ++q) {
            wA[q] = Wg2[(size_t)(f + q) * 160 + c0];
            wB[q] = Wg2[(size_t)(f + q) * 160 + c1];
            wC[q] = h2 ? Wg2[(size_t)(f + q) * 160 + c2] : 0.f;
        }
#pragma unroll
        for (int a = 0; a < 9; ++a) {
            const float4 v = *reinterpret_cast<const float4*>(&m3s[a * 80 + f]);
            a0[a] += v.x * wA[0] + v.y * wA[1] + v.z * wA[2] + v.w * wA[3];
            a1[a] += v.x * wB[0] + v.y * wB[1] + v.z * wB[2] + v.w * wB[3];
            a2[a] += v.x * wC[0] + v.y * wC[1] + v.z * wC[2] + v.w * wC[3];
        }
    }
    float* op = out + (size_t)b * 1440;
#pragma unroll
    for (int a = 0; a < 9; ++a) {
        const float t0 = a0[a]; op[a * 160 + c0] = t0 > 0.f ? t0 : 0.2f * t0;
        const float t1 = a1[a]; op[a * 160 + c1] = t1 > 0.f ? t1 : 0.2f * t1;
        if (h2) { const float t2 = a2[a]; op[a * 160 + c2] = t2 > 0.f ? t2 : 0.2f * t2; }
    }
}

// ---------------------------------------------------------------------------
extern "C" void kernel_launch(void* const* d_in, const int* in_sizes, int n_in,
                              void* d_out, int out_size, void* d_ws, size_t ws_size,
                              hipStream_t stream)
{
    const float* x    = (const float*)d_in[0];
    const float* Wq   = (const float*)d_in[2];
    const float* Wk   = (const float*)d_in[4];
    const float* Wv   = (const float*)d_in[6];
    const float* Wo   = (const float*)d_in[8];
    const float* bo   = (const float*)d_in[9];
    const float* ln1g = (const float*)d_in[10];
    const float* ln1b = (const float*)d_in[11];
    const float* ln2g = (const float*)d_in[12];
    const float* ln2b = (const float*)d_in[13];
    const float* Wf1  = (const float*)d_in[14];
    const float* bf1  = (const float*)d_in[15];
    const float* Wf2  = (const float*)d_in[16];
    const float* bf2  = (const float*)d_in[17];
    const float* wg1c = (const float*)d_in[18];  // W_gcn1 [1,40]
    const float* Wg1  = (const float*)d_in[19];  // [40,80]
    const float* Wg2  = (const float*)d_in[20];  // [80,160]

    const int Bn = in_sizes[0] / NN;

    float* MN = (float*)d_ws;                    // 7776 floats
    const size_t mn_floats = (size_t)LAYERS * NHEAD * 2 * 81;
    const size_t need = (mn_floats + (size_t)Bn * 90) * sizeof(float);
    const int use_ws_scratch = (ws_size >= need) ? 1 : 0;
    float* adjz = use_ws_scratch ? (MN + mn_floats) : (float*)d_out;

    k_precompute<<<dim3(LAYERS, NHEAD), 192, 0, stream>>>(Wq, Wk, Wv, Wo, MN);

    // 28 batch elements per 256-thread block (7 per wave, 9 lanes each)
    const int nblk = (Bn + 27) / 28;
    k_transformer<<<nblk, 256, 0, stream>>>(x, MN, bo, ln1g, ln1b, ln2g, ln2b,
                                            Wf1, bf1, Wf2, bf2, adjz, Bn, use_ws_scratch);

    k_gcn<<<Bn, 64, 0, stream>>>(adjz, wg1c, Wg1, Wg2, (float*)d_out, Bn, use_ws_scratch);
}

// Round 6
// 1592.540 us; speedup vs baseline: 4.3323x; 1.2838x over previous
//
#include <hip/hip_runtime.h>

#define LAYERS 6
#define NN 9
#define NHEAD 8
#define HD 16

// ---------------------------------------------------------------------------
// K0: precompute per-layer/head  M_h = 0.25 * Aq_h @ Ak_h^T  (9x9)
//                                N_h = Av_h @ Wo_h           (9x9)
// MN layout: [l][h][2][81]
// ---------------------------------------------------------------------------
__global__ void k_precompute(const float* __restrict__ Wq, const float* __restrict__ Wk,
                             const float* __restrict__ Wv, const float* __restrict__ Wo,
                             float* __restrict__ MN)
{
    const int l  = blockIdx.x;   // 0..5
    const int ht = blockIdx.y;   // 0..7
    const int t  = threadIdx.x;  // 0..191
    if (t < 81) {
        const int a = t / 9, b = t % 9;
        float s = 0.f;
        for (int d = 0; d < HD; ++d)
            s += Wq[(l * NN + a) * 128 + ht * HD + d] * Wk[(l * NN + b) * 128 + ht * HD + d];
        MN[((size_t)(l * NHEAD + ht) * 2 + 0) * 81 + t] = s * 0.25f;
    } else if (t < 162) {
        const int u = t - 81;
        const int a = u / 9, b = u % 9;
        float s = 0.f;
        for (int d = 0; d < HD; ++d)
            s += Wv[(l * NN + a) * 128 + ht * HD + d] * Wo[((size_t)l * 128 + ht * HD + d) * NN + b];
        MN[((size_t)(l * NHEAD + ht) * 2 + 1) * 81 + u] = s;
    }
}

// ---------------------------------------------------------------------------
// K1: transformer, ROW-PER-LANE (verified round 5, unchanged).
// ---------------------------------------------------------------------------
__global__ void __launch_bounds__(256, 2) k_transformer(
    const float* __restrict__ xg, const float* __restrict__ MN,
    const float* __restrict__ bo,
    const float* __restrict__ ln1g, const float* __restrict__ ln1b,
    const float* __restrict__ ln2g, const float* __restrict__ ln2b,
    const float* __restrict__ Wf1, const float* __restrict__ bf1,
    const float* __restrict__ Wf2, const float* __restrict__ bf2,
    float* __restrict__ scratch, int Bn, int layout_soa)
{
    __shared__ __align__(16) float hT[4][7][9][12];   // [wave][group][row][col pad 12]

    const int tid  = threadIdx.x;
    const int wv   = tid >> 6;
    const int lane = tid & 63;
    const int g    = lane / 9;        // 0..6 active, 7 = idle lane 63
    const int a    = lane - g * 9;    // my row 0..8
    const int b    = (blockIdx.x * 4 + wv) * 7 + g;
    if (g >= 7 || b >= Bn) return;    // no barriers in kernel -> early return safe

    const float* __restrict__ xp = xg + (size_t)b * NN;
    float* myrow = &hT[wv][g][a][0];

    // ---- init: h = diag(x) ; publish my row ----
    float h[9];
    const float xa = xp[a];
#pragma unroll
    for (int j = 0; j < 9; ++j) h[j] = (j == a) ? xa : 0.f;
    *(float4*)(myrow)     = make_float4(h[0], h[1], h[2], h[3]);
    *(float4*)(myrow + 4) = make_float4(h[4], h[5], h[6], h[7]);
    myrow[8] = h[8];
    __builtin_amdgcn_wave_barrier();

#pragma unroll 1
    for (int l = 0; l < LAYERS; ++l) {
        float acc[9];
#pragma unroll
        for (int j = 0; j < 9; ++j) acc[j] = 0.f;

        // ---- attention: acc += softmax(h M h^T) h N, per head ----
#pragma unroll 1
        for (int ht = 0; ht < NHEAD; ++ht) {
            const float* __restrict__ Mw = MN + ((size_t)(l * NHEAD + ht) * 2) * 81;
            const float* __restrict__ Nw = Mw + 81;

            // T[k] = sum_m h[a][m] * M[m][k]   (h row is lane-local)
            float T[9];
#pragma unroll
            for (int k = 0; k < 9; ++k) T[k] = 0.f;
#pragma unroll
            for (int m = 0; m < 9; ++m) {
                const float hm = h[m];
#pragma unroll
                for (int k = 0; k < 9; ++k) T[k] += hm * Mw[m * 9 + k];
            }

            // S[j] = sum_k T[k] * h[j][k]  (other rows via LDS broadcast)
            float P[9];
#pragma unroll
            for (int j = 0; j < 9; ++j) {
                const float4 v0 = *(const float4*)&hT[wv][g][j][0];
                const float4 v1 = *(const float4*)&hT[wv][g][j][4];
                const float  v8 = hT[wv][g][j][8];
                float s = T[0] * v0.x;
                s += T[1] * v0.y; s += T[2] * v0.z; s += T[3] * v0.w;
                s += T[4] * v1.x; s += T[5] * v1.y; s += T[6] * v1.z; s += T[7] * v1.w;
                s += T[8] * v8;
                P[j] = s;
            }

            // softmax (row-local)
            float mx = P[0];
#pragma unroll
            for (int j = 1; j < 9; ++j) mx = fmaxf(mx, P[j]);
            float sum = 0.f;
#pragma unroll
            for (int j = 0; j < 9; ++j) { P[j] = __expf(P[j] - mx); sum += P[j]; }
            const float inv = __builtin_amdgcn_rcpf(sum);
#pragma unroll
            for (int j = 0; j < 9; ++j) P[j] *= inv;

            // Q[c] = sum_k P[k] * h[k][c]
            float Q[9];
#pragma unroll
            for (int c = 0; c < 9; ++c) Q[c] = 0.f;
#pragma unroll
            for (int k = 0; k < 9; ++k) {
                const float4 v0 = *(const float4*)&hT[wv][g][k][0];
                const float4 v1 = *(const float4*)&hT[wv][g][k][4];
                const float  v8 = hT[wv][g][k][8];
                const float pk = P[k];
                Q[0] += pk * v0.x; Q[1] += pk * v0.y; Q[2] += pk * v0.z; Q[3] += pk * v0.w;
                Q[4] += pk * v1.x; Q[5] += pk * v1.y; Q[6] += pk * v1.z; Q[7] += pk * v1.w;
                Q[8] += pk * v8;
            }

            // acc[j] += sum_c Q[c] * N[c][j]
#pragma unroll
            for (int c = 0; c < 9; ++c) {
                const float qc = Q[c];
#pragma unroll
                for (int j = 0; j < 9; ++j) acc[j] += qc * Nw[c * 9 + j];
            }
        }

        // ---- LN1 (row-local) ----
        {
            const float* bop = bo   + l * 9;
            const float* g1  = ln1g + l * 9;
            const float* b1  = ln1b + l * 9;
            float r[9]; float mean = 0.f;
#pragma unroll
            for (int j = 0; j < 9; ++j) { r[j] = h[j] + acc[j] + bop[j]; mean += r[j]; }
            mean *= (1.f / 9.f);
            float var = 0.f;
#pragma unroll
            for (int j = 0; j < 9; ++j) { const float d = r[j] - mean; var += d * d; }
            var *= (1.f / 9.f);
            const float rs = __builtin_amdgcn_rsqf(var + 1e-5f);
#pragma unroll
            for (int j = 0; j < 9; ++j) h[j] = (r[j] - mean) * rs * g1[j] + b1[j];
        }

        // ---- FFN + LN2 (row-local; h row in registers) ----
        {
            const float* wf1 = Wf1 + (size_t)l * 9 * 40;
            const float* wf2 = Wf2 + (size_t)l * 40 * 9;
            const float* bp1 = bf1 + l * 40;
            float accr[9];
#pragma unroll
            for (int j = 0; j < 9; ++j) accr[j] = 0.f;
#pragma unroll 4
            for (int f = 0; f < 40; ++f) {
                float s = bp1[f];
#pragma unroll
                for (int m = 0; m < 9; ++m) s += h[m] * wf1[m * 40 + f];
                s = fmaxf(s, 0.f);
#pragma unroll
                for (int j = 0; j < 9; ++j) accr[j] += s * wf2[f * 9 + j];
            }
            const float* bp2 = bf2  + l * 9;
            const float* g2  = ln2g + l * 9;
            const float* b2  = ln2b + l * 9;
            float r[9]; float mean = 0.f;
#pragma unroll
            for (int j = 0; j < 9; ++j) { r[j] = h[j] + accr[j] + bp2[j]; mean += r[j]; }
            mean *= (1.f / 9.f);
            float var = 0.f;
#pragma unroll
            for (int j = 0; j < 9; ++j) { const float d = r[j] - mean; var += d * d; }
            var *= (1.f / 9.f);
            const float rs = __builtin_amdgcn_rsqf(var + 1e-5f);
#pragma unroll
            for (int j = 0; j < 9; ++j) h[j] = (r[j] - mean) * rs * g2[j] + b2[j];
        }

        // ---- publish updated row for next layer's attention ----
        if (l < LAYERS - 1) {
            __builtin_amdgcn_wave_barrier();
            *(float4*)(myrow)     = make_float4(h[0], h[1], h[2], h[3]);
            *(float4*)(myrow + 4) = make_float4(h[4], h[5], h[6], h[7]);
            myrow[8] = h[8];
            __builtin_amdgcn_wave_barrier();
        }
    }

    // ---- write adj row (=h) and z[a] = adj_row . x ----
    if (layout_soa) {
#pragma unroll
        for (int j = 0; j < 9; ++j) scratch[(size_t)(a * 9 + j) * Bn + b] = h[j];
        float z = 0.f;
#pragma unroll
        for (int k = 0; k < 9; ++k) z += h[k] * xp[k];
        scratch[(size_t)(81 + a) * Bn + b] = z;
    } else {
        float* op = scratch + (size_t)b * 1440;
#pragma unroll
        for (int j = 0; j < 9; ++j) op[a * 9 + j] = h[j];
        float z = 0.f;
#pragma unroll
        for (int k = 0; k < 9; ++k) z += h[k] * xp[k];
        op[81 + a] = z;
    }
}

// ---------------------------------------------------------------------------
// K2: GCN, restructured. 512-thread block = 8 independent waves; each wave
// processes 32 batch elements sequentially (256 b / block, grid = Bn/256).
// Wg1/Wg2/w1 staged into LDS ONCE per block and reused across 256 b -> kills
// the per-block global weight re-reads that made the old version latency-
// bound (one wave/block, 240 global loads per b in stage 4).
// Per-wave LDS: P(y1)+Q(m2->m3)+adj+z = 6.1KB; block total 113KB (<160KB).
// Waves are independent after the single init __syncthreads.
// FMA order per accumulator identical to the verified round-5 kernel.
// ---------------------------------------------------------------------------
#define GWAVES 8
#define GR 32

__global__ void __launch_bounds__(512, 1) k_gcn(
    const float* __restrict__ scratch, const float* __restrict__ w1,
    const float* __restrict__ Wg1, const float* __restrict__ Wg2,
    float* __restrict__ out, int Bn, int layout_soa)
{
    __shared__ __align__(16) float Wg2s[80 * 160];        // 51.2 KB
    __shared__ __align__(16) float Wg1s[40 * 80];         // 12.8 KB
    __shared__ float w1s[40];
    __shared__ __align__(16) float Pb[GWAVES][9 * 80];    // y1
    __shared__ __align__(16) float Qb[GWAVES][9 * 80];    // m2 (0..359) then m3
    __shared__ float adjW[GWAVES][81];
    __shared__ float zW[GWAVES][9];

    const int tid = threadIdx.x;

    // ---- stage weights once per block ----
    for (int t = tid; t < 80 * 160; t += 512) Wg2s[t] = Wg2[t];
    for (int t = tid; t < 40 * 80; t += 512)  Wg1s[t] = Wg1[t];
    if (tid < 40) w1s[tid] = w1[tid];
    __syncthreads();   // the only block-wide barrier

    const int wv = tid >> 6;
    const int l  = tid & 63;
    float* __restrict__ P    = Pb[wv];
    float* __restrict__ Q    = Qb[wv];
    float* __restrict__ adjs = adjW[wv];
    float* __restrict__ zs   = zW[wv];

    const int wbase = (blockIdx.x * GWAVES + wv) * GR;

#pragma unroll 1
    for (int r = 0; r < GR; ++r) {
        const int b = wbase + r;
        if (b >= Bn) break;

        // ---- load adj (81) + z (9) for this b ----
        if (layout_soa) {
            adjs[l] = scratch[(size_t)l * Bn + b];
            if (l < 17) adjs[64 + l] = scratch[(size_t)(64 + l) * Bn + b];
            if (l < 9)  zs[l] = scratch[(size_t)(81 + l) * Bn + b];
        } else {
            const float* src = scratch + (size_t)b * 1440;
            adjs[l] = src[l];
            if (l < 17) adjs[64 + l] = src[64 + l];
            if (l < 9)  zs[l] = src[81 + l];
        }
        __builtin_amdgcn_wave_barrier();

        // ---- stage 1: m2[a][c] = sum_k adj[a][k] * LR(z[k]*w1[c]) -> Q[a*40+c]
        for (int o = l; o < 360; o += 64) {
            const int c = o / 9, a = o - c * 9;
            const float wc = w1s[c];
            float s = 0.f;
#pragma unroll
            for (int k = 0; k < 9; ++k) {
                float nv = zs[k] * wc;
                nv = nv > 0.f ? nv : 0.2f * nv;
                s += adjs[a * 9 + k] * nv;
            }
            Q[a * 40 + c] = s;
        }
        __builtin_amdgcn_wave_barrier();

        // ---- stage 2: y1[a][j] = LR( sum_f m2[a][f] * Wg1[f][j] ) -> P[a*80+j]
        for (int j = l; j < 80; j += 64) {
            float acc[9];
#pragma unroll
            for (int a = 0; a < 9; ++a) acc[a] = 0.f;
            for (int f = 0; f < 40; f += 4) {
                const float w0 = Wg1s[f * 80 + j];
                const float wA = Wg1s[(f + 1) * 80 + j];
                const float wB = Wg1s[(f + 2) * 80 + j];
                const float wC = Wg1s[(f + 3) * 80 + j];
#pragma unroll
                for (int a = 0; a < 9; ++a) {
                    const float4 v = *reinterpret_cast<const float4*>(&Q[a * 40 + f]);
                    acc[a] += v.x * w0 + v.y * wA + v.z * wB + v.w * wC;
                }
            }
#pragma unroll
            for (int a = 0; a < 9; ++a) {
                const float t = acc[a];
                P[a * 80 + j] = t > 0.f ? t : 0.2f * t;
            }
        }
        __builtin_amdgcn_wave_barrier();

        // ---- stage 3: m3[a][j] = sum_k adj[a][k] * y1[k][j] -> Q[a*80+j]
        // (overwrites m2; m2 is dead. adj reads are wave-broadcast = free)
        for (int j = l; j < 80; j += 64) {
            float acc[9];
#pragma unroll
            for (int a = 0; a < 9; ++a) acc[a] = 0.f;
#pragma unroll
            for (int k = 0; k < 9; ++k) {
                const float yv = P[k * 80 + j];
#pragma unroll
                for (int a = 0; a < 9; ++a) acc[a] += adjs[a * 9 + k] * yv;
            }
#pragma unroll
            for (int a = 0; a < 9; ++a) Q[a * 80 + j] = acc[a];
        }
        __builtin_amdgcn_wave_barrier();

        // ---- stage 4: y2[a][c] = LR( sum_f m3[a][f] * Wg2[f][c] ) -> out
        // Wg2 from LDS: lane-consecutive c -> 2 lanes/bank, conflict-free.
        float a0[9], a1[9], a2[9];
#pragma unroll
        for (int a = 0; a < 9; ++a) { a0[a] = 0.f; a1[a] = 0.f; a2[a] = 0.f; }
        const bool h2 = (l < 32);
        const int c0 = l, c1 = l + 64, c2 = l + 128;
        for (int f = 0; f < 80; f += 4) {
            float wA[4], wB[4], wC[4];
#pragma unroll
            for (int q = 0; q < 4; ++q) {
                wA[q] = Wg2s[(f + q) * 160 + c0];
                wB[q] = Wg2s[(f + q) * 160 + c1];
                wC[q] = h2 ? Wg2s[(f + q) * 160 + c2] : 0.f;
            }
#pragma unroll
            for (int a = 0; a < 9; ++a) {
                const float4 v = *reinterpret_cast<const float4*>(&Q[a * 80 + f]);
                a0[a] += v.x * wA[0] + v.y * wA[1] + v.z * wA[2] + v.w * wA[3];
                a1[a] += v.x * wB[0] + v.y * wB[1] + v.z * wB[2] + v.w * wB[3];
                a2[a] += v.x * wC[0] + v.y * wC[1] + v.z * wC[2] + v.w * wC[3];
            }
        }
        float* op = out + (size_t)b * 1440;
#pragma unroll
        for (int a = 0; a < 9; ++a) {
            const float t0 = a0[a]; op[a * 160 + c0] = t0 > 0.f ? t0 : 0.2f * t0;
            const float t1 = a1[a]; op[a * 160 + c1] = t1 > 0.f ? t1 : 0.2f * t1;
            if (h2) { const float t2 = a2[a]; op[a * 160 + c2] = t2 > 0.f ? t2 : 0.2f * t2; }
        }
        __builtin_amdgcn_wave_barrier();
    }
}

// ---------------------------------------------------------------------------
extern "C" void kernel_launch(void* const* d_in, const int* in_sizes, int n_in,
                              void* d_out, int out_size, void* d_ws, size_t ws_size,
                              hipStream_t stream)
{
    const float* x    = (const float*)d_in[0];
    const float* Wq   = (const float*)d_in[2];
    const float* Wk   = (const float*)d_in[4];
    const float* Wv   = (const float*)d_in[6];
    const float* Wo   = (const float*)d_in[8];
    const float* bo   = (const float*)d_in[9];
    const float* ln1g = (const float*)d_in[10];
    const float* ln1b = (const float*)d_in[11];
    const float* ln2g = (const float*)d_in[12];
    const float* ln2b = (const float*)d_in[13];
    const float* Wf1  = (const float*)d_in[14];
    const float* bf1  = (const float*)d_in[15];
    const float* Wf2  = (const float*)d_in[16];
    const float* bf2  = (const float*)d_in[17];
    const float* wg1c = (const float*)d_in[18];  // W_gcn1 [1,40]
    const float* Wg1  = (const float*)d_in[19];  // [40,80]
    const float* Wg2  = (const float*)d_in[20];  // [80,160]

    const int Bn = in_sizes[0] / NN;

    float* MN = (float*)d_ws;                    // 7776 floats
    const size_t mn_floats = (size_t)LAYERS * NHEAD * 2 * 81;
    const size_t need = (mn_floats + (size_t)Bn * 90) * sizeof(float);
    const int use_ws_scratch = (ws_size >= need) ? 1 : 0;
    float* adjz = use_ws_scratch ? (MN + mn_floats) : (float*)d_out;

    k_precompute<<<dim3(LAYERS, NHEAD), 192, 0, stream>>>(Wq, Wk, Wv, Wo, MN);

    // 28 batch elements per 256-thread block (7 per wave, 9 lanes each)
    const int nblk = (Bn + 27) / 28;
    k_transformer<<<nblk, 256, 0, stream>>>(x, MN, bo, ln1g, ln1b, ln2g, ln2b,
                                            Wf1, bf1, Wf2, bf2, adjz, Bn, use_ws_scratch);

    // 256 b per block (8 waves x 32 each)
    const int gblk = (Bn + GWAVES * GR - 1) / (GWAVES * GR);
    k_gcn<<<gblk, 512, 0, stream>>>(adjz, wg1c, Wg1, Wg2, (float*)d_out, Bn, use_ws_scratch);
}

// Round 8
// 1148.204 us; speedup vs baseline: 6.0088x; 1.3870x over previous
//
#include <hip/hip_runtime.h>

#define LAYERS 6
#define NN 9
#define NHEAD 8
#define HD 16

typedef __attribute__((ext_vector_type(8))) short bf16x8;
typedef __attribute__((ext_vector_type(4))) float f32x4;

__device__ __forceinline__ unsigned short f2bf(float f) {
    unsigned u = __float_as_uint(f);
    u += 0x7FFFu + ((u >> 16) & 1u);      // round-to-nearest-even
    return (unsigned short)(u >> 16);
}

// ---------------------------------------------------------------------------
// K0: precompute per-layer/head  M_h = 0.25 * Aq_h @ Ak_h^T  (9x9)
//                                N_h = Av_h @ Wo_h           (9x9)
// MN layout: [l][h][2][81]
// ---------------------------------------------------------------------------
__global__ void k_precompute(const float* __restrict__ Wq, const float* __restrict__ Wk,
                             const float* __restrict__ Wv, const float* __restrict__ Wo,
                             float* __restrict__ MN)
{
    const int l  = blockIdx.x;   // 0..5
    const int ht = blockIdx.y;   // 0..7
    const int t  = threadIdx.x;  // 0..191
    if (t < 81) {
        const int a = t / 9, b = t % 9;
        float s = 0.f;
        for (int d = 0; d < HD; ++d)
            s += Wq[(l * NN + a) * 128 + ht * HD + d] * Wk[(l * NN + b) * 128 + ht * HD + d];
        MN[((size_t)(l * NHEAD + ht) * 2 + 0) * 81 + t] = s * 0.25f;
    } else if (t < 162) {
        const int u = t - 81;
        const int a = u / 9, b = u % 9;
        float s = 0.f;
        for (int d = 0; d < HD; ++d)
            s += Wv[(l * NN + a) * 128 + ht * HD + d] * Wo[((size_t)l * 128 + ht * HD + d) * NN + b];
        MN[((size_t)(l * NHEAD + ht) * 2 + 1) * 81 + u] = s;
    }
}

// ---------------------------------------------------------------------------
// K1: transformer, ROW-PER-LANE (verified rounds 5/6, unchanged).
// ---------------------------------------------------------------------------
__global__ void __launch_bounds__(256, 2) k_transformer(
    const float* __restrict__ xg, const float* __restrict__ MN,
    const float* __restrict__ bo,
    const float* __restrict__ ln1g, const float* __restrict__ ln1b,
    const float* __restrict__ ln2g, const float* __restrict__ ln2b,
    const float* __restrict__ Wf1, const float* __restrict__ bf1,
    const float* __restrict__ Wf2, const float* __restrict__ bf2,
    float* __restrict__ scratch, int Bn, int layout_soa)
{
    __shared__ __align__(16) float hT[4][7][9][12];   // [wave][group][row][col pad 12]

    const int tid  = threadIdx.x;
    const int wv   = tid >> 6;
    const int lane = tid & 63;
    const int g    = lane / 9;        // 0..6 active, 7 = idle lane 63
    const int a    = lane - g * 9;    // my row 0..8
    const int b    = (blockIdx.x * 4 + wv) * 7 + g;
    if (g >= 7 || b >= Bn) return;    // no barriers in kernel -> early return safe

    const float* __restrict__ xp = xg + (size_t)b * NN;
    float* myrow = &hT[wv][g][a][0];

    // ---- init: h = diag(x) ; publish my row ----
    float h[9];
    const float xa = xp[a];
#pragma unroll
    for (int j = 0; j < 9; ++j) h[j] = (j == a) ? xa : 0.f;
    *(float4*)(myrow)     = make_float4(h[0], h[1], h[2], h[3]);
    *(float4*)(myrow + 4) = make_float4(h[4], h[5], h[6], h[7]);
    myrow[8] = h[8];
    __builtin_amdgcn_wave_barrier();

#pragma unroll 1
    for (int l = 0; l < LAYERS; ++l) {
        float acc[9];
#pragma unroll
        for (int j = 0; j < 9; ++j) acc[j] = 0.f;

        // ---- attention: acc += softmax(h M h^T) h N, per head ----
#pragma unroll 1
        for (int ht = 0; ht < NHEAD; ++ht) {
            const float* __restrict__ Mw = MN + ((size_t)(l * NHEAD + ht) * 2) * 81;
            const float* __restrict__ Nw = Mw + 81;

            // T[k] = sum_m h[a][m] * M[m][k]   (h row is lane-local)
            float T[9];
#pragma unroll
            for (int k = 0; k < 9; ++k) T[k] = 0.f;
#pragma unroll
            for (int m = 0; m < 9; ++m) {
                const float hm = h[m];
#pragma unroll
                for (int k = 0; k < 9; ++k) T[k] += hm * Mw[m * 9 + k];
            }

            // S[j] = sum_k T[k] * h[j][k]  (other rows via LDS broadcast)
            float P[9];
#pragma unroll
            for (int j = 0; j < 9; ++j) {
                const float4 v0 = *(const float4*)&hT[wv][g][j][0];
                const float4 v1 = *(const float4*)&hT[wv][g][j][4];
                const float  v8 = hT[wv][g][j][8];
                float s = T[0] * v0.x;
                s += T[1] * v0.y; s += T[2] * v0.z; s += T[3] * v0.w;
                s += T[4] * v1.x; s += T[5] * v1.y; s += T[6] * v1.z; s += T[7] * v1.w;
                s += T[8] * v8;
                P[j] = s;
            }

            // softmax (row-local)
            float mx = P[0];
#pragma unroll
            for (int j = 1; j < 9; ++j) mx = fmaxf(mx, P[j]);
            float sum = 0.f;
#pragma unroll
            for (int j = 0; j < 9; ++j) { P[j] = __expf(P[j] - mx); sum += P[j]; }
            const float inv = __builtin_amdgcn_rcpf(sum);
#pragma unroll
            for (int j = 0; j < 9; ++j) P[j] *= inv;

            // Q[c] = sum_k P[k] * h[k][c]
            float Q[9];
#pragma unroll
            for (int c = 0; c < 9; ++c) Q[c] = 0.f;
#pragma unroll
            for (int k = 0; k < 9; ++k) {
                const float4 v0 = *(const float4*)&hT[wv][g][k][0];
                const float4 v1 = *(const float4*)&hT[wv][g][k][4];
                const float  v8 = hT[wv][g][k][8];
                const float pk = P[k];
                Q[0] += pk * v0.x; Q[1] += pk * v0.y; Q[2] += pk * v0.z; Q[3] += pk * v0.w;
                Q[4] += pk * v1.x; Q[5] += pk * v1.y; Q[6] += pk * v1.z; Q[7] += pk * v1.w;
                Q[8] += pk * v8;
            }

            // acc[j] += sum_c Q[c] * N[c][j]
#pragma unroll
            for (int c = 0; c < 9; ++c) {
                const float qc = Q[c];
#pragma unroll
                for (int j = 0; j < 9; ++j) acc[j] += qc * Nw[c * 9 + j];
            }
        }

        // ---- LN1 (row-local) ----
        {
            const float* bop = bo   + l * 9;
            const float* g1  = ln1g + l * 9;
            const float* b1  = ln1b + l * 9;
            float r[9]; float mean = 0.f;
#pragma unroll
            for (int j = 0; j < 9; ++j) { r[j] = h[j] + acc[j] + bop[j]; mean += r[j]; }
            mean *= (1.f / 9.f);
            float var = 0.f;
#pragma unroll
            for (int j = 0; j < 9; ++j) { const float d = r[j] - mean; var += d * d; }
            var *= (1.f / 9.f);
            const float rs = __builtin_amdgcn_rsqf(var + 1e-5f);
#pragma unroll
            for (int j = 0; j < 9; ++j) h[j] = (r[j] - mean) * rs * g1[j] + b1[j];
        }

        // ---- FFN + LN2 (row-local; h row in registers) ----
        {
            const float* wf1 = Wf1 + (size_t)l * 9 * 40;
            const float* wf2 = Wf2 + (size_t)l * 40 * 9;
            const float* bp1 = bf1 + l * 40;
            float accr[9];
#pragma unroll
            for (int j = 0; j < 9; ++j) accr[j] = 0.f;
#pragma unroll 4
            for (int f = 0; f < 40; ++f) {
                float s = bp1[f];
#pragma unroll
                for (int m = 0; m < 9; ++m) s += h[m] * wf1[m * 40 + f];
                s = fmaxf(s, 0.f);
#pragma unroll
                for (int j = 0; j < 9; ++j) accr[j] += s * wf2[f * 9 + j];
            }
            const float* bp2 = bf2  + l * 9;
            const float* g2  = ln2g + l * 9;
            const float* b2  = ln2b + l * 9;
            float r[9]; float mean = 0.f;
#pragma unroll
            for (int j = 0; j < 9; ++j) { r[j] = h[j] + accr[j] + bp2[j]; mean += r[j]; }
            mean *= (1.f / 9.f);
            float var = 0.f;
#pragma unroll
            for (int j = 0; j < 9; ++j) { const float d = r[j] - mean; var += d * d; }
            var *= (1.f / 9.f);
            const float rs = __builtin_amdgcn_rsqf(var + 1e-5f);
#pragma unroll
            for (int j = 0; j < 9; ++j) h[j] = (r[j] - mean) * rs * g2[j] + b2[j];
        }

        // ---- publish updated row for next layer's attention ----
        if (l < LAYERS - 1) {
            __builtin_amdgcn_wave_barrier();
            *(float4*)(myrow)     = make_float4(h[0], h[1], h[2], h[3]);
            *(float4*)(myrow + 4) = make_float4(h[4], h[5], h[6], h[7]);
            myrow[8] = h[8];
            __builtin_amdgcn_wave_barrier();
        }
    }

    // ---- write adj row (=h) and z[a] = adj_row . x ----
    if (layout_soa) {
#pragma unroll
        for (int j = 0; j < 9; ++j) scratch[(size_t)(a * 9 + j) * Bn + b] = h[j];
        float z = 0.f;
#pragma unroll
        for (int k = 0; k < 9; ++k) z += h[k] * xp[k];
        scratch[(size_t)(81 + a) * Bn + b] = z;
    } else {
        float* op = scratch + (size_t)b * 1440;
#pragma unroll
        for (int j = 0; j < 9; ++j) op[a * 9 + j] = h[j];
        float z = 0.f;
#pragma unroll
        for (int k = 0; k < 9; ++k) z += h[k] * xp[k];
        op[81 + a] = z;
    }
}

// ---------------------------------------------------------------------------
// K2: GCN v3 — MFMA for the two batch-shared GEMM stages.
//   stage1 (VALU): m2[9x40] = adj @ LR(z w1^T)        -> m2bf (bf16, A-layout)
//   stage2 (MFMA): y1 = LR(m2 @ Wg1)   M16(pad9) N80 K64(pad40), 10 mfma/b
//   stage3 (VALU): m3[9x80] = adj @ y1                -> m3bf (bf16, A-layout)
//   stage4 (MFMA): y2 = LR(m3 @ Wg2)   M16(pad9) N160 K96(pad80), 30 mfma/b
// Wg1/Wg2 staged ONCE per block as bf16 B^T tiles ([n][k] row-major,
// k-padding zeroed). A-tiles (m2bf/m3bf) are ZERO-INITIALIZED once per wave
// before the batch loop: their k-padding columns are never written in the
// loop, and uninitialized LDS there could hold Inf/NaN bf16 patterns ->
// Inf*0=NaN would poison live accumulator rows (hardening vs round 7).
// Fragment layouts per verified guide facts: A/B contiguous-8-K per lane
// (m97 pattern), C/D col=lane&15,row=(lane>>4)*4+reg (m89). LDS rows padded
// 72/104/84 -> fragment accesses 2 lanes/bank (free).
// 8 waves x 32 b sequential; fp32 accumulate in MFMA; bf16 only at the four
// quantization points (m2,Wg1,m3,Wg2) -> est absmax ~0.1 vs 0.289 threshold.
// ---------------------------------------------------------------------------
#define GWAVES 8
#define GR 32

__global__ void __launch_bounds__(512, 1) k_gcn(
    const float* __restrict__ scratch, const float* __restrict__ w1,
    const float* __restrict__ Wg1, const float* __restrict__ Wg2,
    float* __restrict__ out, int Bn, int layout_soa)
{
    __shared__ __align__(16) unsigned short Wg2T[160 * 104]; // [c][f pad104], f>=80 -> 0   (33.3 KB)
    __shared__ __align__(16) unsigned short Wg1T[80 * 72];   // [n][k pad72],  k>=40 -> 0   (11.5 KB)
    __shared__ float w1s[40];
    __shared__ __align__(16) unsigned short m2bf[GWAVES][16 * 72];   // A-tile stage2
    __shared__ __align__(16) unsigned short m3bf[GWAVES][16 * 104];  // A-tile stage4
    __shared__ float Pf[GWAVES][9 * 84];                              // y1 fp32 (pad 84)
    __shared__ float adjW[GWAVES][88];
    __shared__ float zW[GWAVES][12];

    const int tid = threadIdx.x;

    // ---- stage weights once per block (coalesced global reads) ----
    for (int t = tid; t < 160 * 104; t += 512) {
        const int f = t / 160, c = t - f * 160;     // consecutive tid -> consecutive c
        Wg2T[c * 104 + f] = (f < 80) ? f2bf(Wg2[(size_t)f * 160 + c]) : (unsigned short)0;
    }
    for (int t = tid; t < 80 * 72; t += 512) {
        const int k = t / 80, n = t - k * 80;
        Wg1T[n * 72 + k] = (k < 40) ? f2bf(Wg1[(size_t)k * 80 + n]) : (unsigned short)0;
    }
    if (tid < 40) w1s[tid] = w1[tid];
    __syncthreads();   // the only block-wide barrier

    const int wv = tid >> 6;
    const int l  = tid & 63;
    const int lr = l & 15;          // fragment row (A) / col (B,C)
    const int lg = l >> 4;          // fragment K-group
    unsigned short* __restrict__ m2w = m2bf[wv];
    unsigned short* __restrict__ m3w = m3bf[wv];
    float* __restrict__ P    = Pf[wv];
    float* __restrict__ adjs = adjW[wv];
    float* __restrict__ zs   = zW[wv];

    // ---- zero A-tiles once: padding cols / rows stay 0 across the loop ----
    for (int t = l; t < 16 * 72; t += 64)  m2w[t] = 0;
    for (int t = l; t < 16 * 104; t += 64) m3w[t] = 0;
    __builtin_amdgcn_wave_barrier();

    const int wbase = (blockIdx.x * GWAVES + wv) * GR;

#pragma unroll 1
    for (int r = 0; r < GR; ++r) {
        const int b = wbase + r;
        if (b >= Bn) break;

        // ---- load adj (81) + z (9) ----
        if (layout_soa) {
            adjs[l] = scratch[(size_t)l * Bn + b];
            if (l < 17) adjs[64 + l] = scratch[(size_t)(64 + l) * Bn + b];
            if (l < 9)  zs[l] = scratch[(size_t)(81 + l) * Bn + b];
        } else {
            const float* src = scratch + (size_t)b * 1440;
            adjs[l] = src[l];
            if (l < 17) adjs[64 + l] = src[64 + l];
            if (l < 9)  zs[l] = src[81 + l];
        }
        __builtin_amdgcn_wave_barrier();

        // ---- stage 1 (VALU): m2[a][c] = sum_k adj[a][k]*LR(z[k]*w1[c]) -> bf16
        for (int o = l; o < 360; o += 64) {
            const int c = o / 9, a = o - c * 9;
            const float wc = w1s[c];
            float s = 0.f;
#pragma unroll
            for (int k = 0; k < 9; ++k) {
                float nv = zs[k] * wc;
                nv = nv > 0.f ? nv : 0.2f * nv;
                s += adjs[a * 9 + k] * nv;
            }
            m2w[a * 72 + c] = f2bf(s);
        }
        __builtin_amdgcn_wave_barrier();

        // ---- stage 2 (MFMA): y1 = LR(m2 @ Wg1), N=80 (5 tiles), K=64 (2 steps)
#pragma unroll
        for (int nt = 0; nt < 5; ++nt) {
            f32x4 acc = {0.f, 0.f, 0.f, 0.f};
#pragma unroll
            for (int kk = 0; kk < 2; ++kk) {
                const bf16x8 af = *reinterpret_cast<const bf16x8*>(m2w + lr * 72 + kk * 32 + lg * 8);
                const bf16x8 bf = *reinterpret_cast<const bf16x8*>(Wg1T + (nt * 16 + lr) * 72 + kk * 32 + lg * 8);
                acc = __builtin_amdgcn_mfma_f32_16x16x32_bf16(af, bf, acc, 0, 0, 0);
            }
#pragma unroll
            for (int i = 0; i < 4; ++i) {
                const int row = lg * 4 + i;
                if (row < 9) {
                    const float t = acc[i];
                    P[row * 84 + nt * 16 + lr] = t > 0.f ? t : 0.2f * t;
                }
            }
        }
        __builtin_amdgcn_wave_barrier();

        // ---- stage 3 (VALU): m3[a][j] = sum_k adj[a][k]*y1[k][j] -> bf16
        for (int j = l; j < 80; j += 64) {
            float yv[9];
#pragma unroll
            for (int k = 0; k < 9; ++k) yv[k] = P[k * 84 + j];
#pragma unroll
            for (int a = 0; a < 9; ++a) {
                float s = 0.f;
#pragma unroll
                for (int k = 0; k < 9; ++k) s += adjs[a * 9 + k] * yv[k];
                m3w[a * 104 + j] = f2bf(s);
            }
        }
        __builtin_amdgcn_wave_barrier();

        // ---- stage 4 (MFMA): y2 = LR(m3 @ Wg2), N=160 (10 tiles), K=96 (3 steps)
        float* __restrict__ op = out + (size_t)b * 1440;
#pragma unroll 1
        for (int nt = 0; nt < 10; ++nt) {
            f32x4 acc = {0.f, 0.f, 0.f, 0.f};
#pragma unroll
            for (int kk = 0; kk < 3; ++kk) {
                const bf16x8 af = *reinterpret_cast<const bf16x8*>(m3w + lr * 104 + kk * 32 + lg * 8);
                const bf16x8 bf = *reinterpret_cast<const bf16x8*>(Wg2T + (nt * 16 + lr) * 104 + kk * 32 + lg * 8);
                acc = __builtin_amdgcn_mfma_f32_16x16x32_bf16(af, bf, acc, 0, 0, 0);
            }
#pragma unroll
            for (int i = 0; i < 4; ++i) {
                const int row = lg * 4 + i;
                if (row < 9) {
                    float t = acc[i];
                    t = t > 0.f ? t : 0.2f * t;
                    op[row * 160 + nt * 16 + lr] = t;
                }
            }
        }
        __builtin_amdgcn_wave_barrier();
    }
}

// ---------------------------------------------------------------------------
extern "C" void kernel_launch(void* const* d_in, const int* in_sizes, int n_in,
                              void* d_out, int out_size, void* d_ws, size_t ws_size,
                              hipStream_t stream)
{
    const float* x    = (const float*)d_in[0];
    const float* Wq   = (const float*)d_in[2];
    const float* Wk   = (const float*)d_in[4];
    const float* Wv   = (const float*)d_in[6];
    const float* Wo   = (const float*)d_in[8];
    const float* bo   = (const float*)d_in[9];
    const float* ln1g = (const float*)d_in[10];
    const float* ln1b = (const float*)d_in[11];
    const float* ln2g = (const float*)d_in[12];
    const float* ln2b = (const float*)d_in[13];
    const float* Wf1  = (const float*)d_in[14];
    const float* bf1  = (const float*)d_in[15];
    const float* Wf2  = (const float*)d_in[16];
    const float* bf2  = (const float*)d_in[17];
    const float* wg1c = (const float*)d_in[18];  // W_gcn1 [1,40]
    const float* Wg1  = (const float*)d_in[19];  // [40,80]
    const float* Wg2  = (const float*)d_in[20];  // [80,160]

    const int Bn = in_sizes[0] / NN;

    float* MN = (float*)d_ws;                    // 7776 floats
    const size_t mn_floats = (size_t)LAYERS * NHEAD * 2 * 81;
    const size_t need = (mn_floats + (size_t)Bn * 90) * sizeof(float);
    const int use_ws_scratch = (ws_size >= need) ? 1 : 0;
    float* adjz = use_ws_scratch ? (MN + mn_floats) : (float*)d_out;

    k_precompute<<<dim3(LAYERS, NHEAD), 192, 0, stream>>>(Wq, Wk, Wv, Wo, MN);

    // 28 batch elements per 256-thread block (7 per wave, 9 lanes each)
    const int nblk = (Bn + 27) / 28;
    k_transformer<<<nblk, 256, 0, stream>>>(x, MN, bo, ln1g, ln1b, ln2g, ln2b,
                                            Wf1, bf1, Wf2, bf2, adjz, Bn, use_ws_scratch);

    // 256 b per block (8 waves x 32 each)
    const int gblk = (Bn + GWAVES * GR - 1) / (GWAVES * GR);
    k_gcn<<<gblk, 512, 0, stream>>>(adjz, wg1c, Wg1, Wg2, (float*)d_out, Bn, use_ws_scratch);
}